// Round 10
// baseline (163.644 us; speedup 1.0000x reference)
//
#include <hip/hip_runtime.h>

typedef __bf16 bf16_t;
typedef __bf16 bf16x8 __attribute__((ext_vector_type(8)));
typedef float f32x4 __attribute__((ext_vector_type(4)));

#define NUM_B 2
#define NUM_H 12
#define SEQ_N 2048
#define DIM_C 768
#define HEAD_D 64
#define BH_CNT (NUM_B * NUM_H)
#define MTOK (NUM_B * SEQ_N)
// qk-scale 1/8 folded with log2(e) so softmax is a bare exp2
#define QSCALE 0.1803368801111137f

#define AS1(p) ((const __attribute__((address_space(1))) void*)(p))
#define AS3(p) ((__attribute__((address_space(3))) void*)(p))

// K'' layout: [bh][c=pos/16][h=d/32] block of 512 = [quad=d%32/8][l16=pos%16][j=d%8]
//   -> attn kf load = base + lane*8 elems (1KB coalesced per fragment)
// V'' layout: [bh][kc=pos/32][dt=d/16] block of 512 = [quad=pos%32/8][l16=d%16][j=pos%8]
//   -> attn vf load = base + lane*8 elems

// ---------------------------------------------------------------------------
// f32 -> bf16 bulk convert (x, qkv_w, proj_w); final NUM_B blocks do the
// mask scan: stable-partition tokens into src[] (visible first, masked pad),
// w'[pos] = 1/0 bf16, cnts[b*2] = cntPad64, cnts[b*2+1] = count.
// ---------------------------------------------------------------------------
__global__ __launch_bounds__(256) void cvt_scan_kernel(
    const float* __restrict__ s0, const float* __restrict__ s1,
    const float* __restrict__ s2, const float* __restrict__ msk,
    bf16_t* __restrict__ d0, bf16_t* __restrict__ d1, bf16_t* __restrict__ d2,
    int* __restrict__ src, bf16_t* __restrict__ wp, int* __restrict__ cnts,
    int nb0, int nb1, int nb2) {
  __shared__ int psum[256];
  const int blk = blockIdx.x;
  const int t = threadIdx.x;
  if (blk >= nb0 + nb1 + nb2) {
    const int b = blk - (nb0 + nb1 + nb2);
    const float* mb = msk + (size_t)b * SEQ_N;
    int vis[8], c = 0;
#pragma unroll
    for (int j = 0; j < 8; ++j) {
      vis[j] = (mb[t * 8 + j] == 0.0f) ? 1 : 0;
      c += vis[j];
    }
    psum[t] = c;
    __syncthreads();
    for (int off = 1; off < 256; off <<= 1) {
      int v = (t >= off) ? psum[t - off] : 0;
      __syncthreads();
      psum[t] += v;
      __syncthreads();
    }
    const int total = psum[255];
    int vpos = psum[t] - c;
    int mpos = total + (t * 8 - (psum[t] - c));
#pragma unroll
    for (int j = 0; j < 8; ++j) {
      const int tok = t * 8 + j;
      if (vis[j]) {
        src[b * SEQ_N + vpos] = b * SEQ_N + tok;
        wp[b * SEQ_N + vpos] = (bf16_t)1.0f;
        ++vpos;
      } else {
        src[b * SEQ_N + mpos] = b * SEQ_N + tok;
        wp[b * SEQ_N + mpos] = (bf16_t)0.0f;
        ++mpos;
      }
    }
    if (t == 0) {
      cnts[b * 2] = (total + 63) & ~63;
      cnts[b * 2 + 1] = total;
    }
    return;
  }
  const float* sp;
  bf16_t* dp;
  size_t off;
  if (blk < nb0) {
    sp = s0; dp = d0; off = (size_t)blk * 2048;
  } else if (blk < nb0 + nb1) {
    sp = s1; dp = d1; off = (size_t)(blk - nb0) * 2048;
  } else {
    sp = s2; dp = d2; off = (size_t)(blk - nb0 - nb1) * 2048;
  }
  const size_t i = off + (size_t)t * 8;
  float4 f0 = *reinterpret_cast<const float4*>(&sp[i]);
  float4 f1 = *reinterpret_cast<const float4*>(&sp[i + 4]);
  union { ushort4 u; bf16_t h[4]; } p0, p1;
  p0.h[0] = (bf16_t)f0.x; p0.h[1] = (bf16_t)f0.y;
  p0.h[2] = (bf16_t)f0.z; p0.h[3] = (bf16_t)f0.w;
  p1.h[0] = (bf16_t)f1.x; p1.h[1] = (bf16_t)f1.y;
  p1.h[2] = (bf16_t)f1.z; p1.h[3] = (bf16_t)f1.w;
  *reinterpret_cast<ushort4*>(&dp[i]) = p0.u;
  *reinterpret_cast<ushort4*>(&dp[i + 4]) = p1.u;
}

// ---------------------------------------------------------------------------
// QKV GEMM (128x128 tile, glls 16B, XOR swizzle, dbuf).
// n0<768: Q (x QSCALE) -> [B,H,N,D].
// 768<=n0<1536: K over compacted rows -> K'' fragment layout.
// n0>=1536: V over compacted rows -> V'' fragment layout (pad keys zeroed).
// K/V blocks fully beyond cntPad64 exit immediately.
// ---------------------------------------------------------------------------
__global__ __launch_bounds__(256, 3) void gemm_qkv_kernel(
    const bf16_t* __restrict__ A, const bf16_t* __restrict__ W,
    const int* __restrict__ src, const int* __restrict__ cnts,
    bf16_t* __restrict__ out) {
  __shared__ __align__(16) bf16_t As[2][128 * 32];
  __shared__ __align__(16) bf16_t Bs[2][128 * 32];

  const int tid = threadIdx.x;
  const int wave = tid >> 6, lane = tid & 63;
  const int quad = lane >> 4, l16 = lane & 15;
  const int m0 = blockIdx.y * 128, n0 = blockIdx.x * 128;
  const int wm = (wave >> 1) * 64, wn = (wave & 1) * 64;
  const bool isQ = (n0 < DIM_C);

  if (!isQ) {
    const int b = m0 >> 11;
    if ((m0 & 2047) >= cnts[b * 2]) return;
  }

  f32x4 acc[4][4] = {};

  const int srow = tid >> 2;
  const int scol = ((tid & 3) ^ ((tid >> 3) & 3)) * 8;
  int ar0, ar1;
  if (isQ) {
    ar0 = m0 + srow;
    ar1 = m0 + srow + 64;
  } else {
    ar0 = src[m0 + srow];
    ar1 = src[m0 + srow + 64];
  }
  const bf16_t* gA0 = A + (size_t)ar0 * DIM_C + scol;
  const bf16_t* gA1 = A + (size_t)ar1 * DIM_C + scol;
  const bf16_t* gB0 = W + (size_t)(n0 + srow) * DIM_C + scol;
  const bf16_t* gB1 = W + (size_t)(n0 + srow + 64) * DIM_C + scol;
  const int lb = wave * 512;

  auto issue = [&](int buf, int k0) {
    __builtin_amdgcn_global_load_lds(AS1(gA0 + k0), AS3(&As[buf][lb]), 16, 0, 0);
    __builtin_amdgcn_global_load_lds(AS1(gA1 + k0), AS3(&As[buf][lb + 2048]), 16, 0, 0);
    __builtin_amdgcn_global_load_lds(AS1(gB0 + k0), AS3(&Bs[buf][lb]), 16, 0, 0);
    __builtin_amdgcn_global_load_lds(AS1(gB1 + k0), AS3(&Bs[buf][lb + 2048]), 16, 0, 0);
  };

  issue(0, 0);
  int cur = 0;
  const int sw = (l16 >> 1) & 3;
  for (int step = 0; step < DIM_C / 32; ++step) {
    __syncthreads();
    if (step + 1 < DIM_C / 32) issue(cur ^ 1, (step + 1) * 32);

    bf16x8 aF[4], bF[4];
#pragma unroll
    for (int mi = 0; mi < 4; ++mi)
      aF[mi] = *reinterpret_cast<const bf16x8*>(
          &As[cur][(wm + mi * 16 + l16) * 32 + ((quad ^ sw) * 8)]);
#pragma unroll
    for (int ni = 0; ni < 4; ++ni)
      bF[ni] = *reinterpret_cast<const bf16x8*>(
          &Bs[cur][(wn + ni * 16 + l16) * 32 + ((quad ^ sw) * 8)]);
#pragma unroll
    for (int mi = 0; mi < 4; ++mi)
#pragma unroll
      for (int ni = 0; ni < 4; ++ni)
        acc[mi][ni] = __builtin_amdgcn_mfma_f32_16x16x32_bf16(aF[mi], bF[ni],
                                                              acc[mi][ni], 0, 0, 0);
    cur ^= 1;
  }

  const size_t per = (size_t)BH_CNT * SEQ_N * HEAD_D;
#pragma unroll
  for (int mi = 0; mi < 4; ++mi) {
#pragma unroll
    for (int ni = 0; ni < 4; ++ni) {
      const int gmB = m0 + wm + mi * 16 + quad * 4;
      const int gn = n0 + wn + ni * 16 + l16;
      const int b = gmB >> 11;
      if (isQ) {
        const int h = gn >> 6, d = gn & 63;
#pragma unroll
        for (int r = 0; r < 4; ++r) {
          const int gm = gmB + r;
          const int tok = gm & 2047;
          out[(((size_t)((gm >> 11) * NUM_H + h) * SEQ_N + tok) * HEAD_D + d)] =
              (bf16_t)(acc[mi][ni][r] * QSCALE);
        }
      } else if (n0 < 2 * DIM_C) {  // K -> K'' fragment layout
        const int rem = gn - DIM_C;
        const int hh = rem >> 6, d = rem & 63;
        const int posm = gmB & 2047;
        const int bh = b * NUM_H + hh;
        const size_t base = per +
            (((size_t)(bh * 128 + (posm >> 4)) * 2 + (d >> 5)) * 512 +
             ((d >> 3) & 3) * 128 + (d & 7));
        const int l16k = posm & 15;
#pragma unroll
        for (int r = 0; r < 4; ++r)
          out[base + (size_t)(l16k + r) * 8] = (bf16_t)acc[mi][ni][r];
      } else {  // V -> V'' fragment layout, zero pad keys
        const int rem = gn - 2 * DIM_C;
        const int hh = rem >> 6, d = rem & 63;
        const int posm = gmB & 2047;
        const int bh = b * NUM_H + hh;
        const int count = cnts[b * 2 + 1];
        const size_t base = 2 * per +
            (((size_t)(bh * 64 + (posm >> 5)) * 4 + (d >> 4)) * 512 +
             ((posm >> 3) & 3) * 128 + (d & 15) * 8 + (posm & 7));
        union { ushort4 u; bf16_t h4[4]; } pk;
#pragma unroll
        for (int r = 0; r < 4; ++r)
          pk.h4[r] = (posm + r < count) ? (bf16_t)acc[mi][ni][r] : (bf16_t)0.0f;
        *reinterpret_cast<ushort4*>(&out[base]) = pk.u;
      }
    }
  }
}

// ---------------------------------------------------------------------------
// Proj GEMM: out = ctx @ proj_w^T + bias, f32 out. 128x128, glls, dbuf.
// ---------------------------------------------------------------------------
__global__ __launch_bounds__(256, 3) void gemm_proj_kernel(
    const bf16_t* __restrict__ A, const bf16_t* __restrict__ W,
    const float* __restrict__ bias, float* __restrict__ out) {
  __shared__ __align__(16) bf16_t As[2][128 * 32];
  __shared__ __align__(16) bf16_t Bs[2][128 * 32];

  const int tid = threadIdx.x;
  const int wave = tid >> 6, lane = tid & 63;
  const int quad = lane >> 4, l16 = lane & 15;
  const int m0 = blockIdx.y * 128, n0 = blockIdx.x * 128;
  const int wm = (wave >> 1) * 64, wn = (wave & 1) * 64;

  f32x4 acc[4][4] = {};

  const int srow = tid >> 2;
  const int scol = ((tid & 3) ^ ((tid >> 3) & 3)) * 8;
  const bf16_t* gA0 = A + (size_t)(m0 + srow) * DIM_C + scol;
  const bf16_t* gA1 = A + (size_t)(m0 + srow + 64) * DIM_C + scol;
  const bf16_t* gB0 = W + (size_t)(n0 + srow) * DIM_C + scol;
  const bf16_t* gB1 = W + (size_t)(n0 + srow + 64) * DIM_C + scol;
  const int lb = wave * 512;

  auto issue = [&](int buf, int k0) {
    __builtin_amdgcn_global_load_lds(AS1(gA0 + k0), AS3(&As[buf][lb]), 16, 0, 0);
    __builtin_amdgcn_global_load_lds(AS1(gA1 + k0), AS3(&As[buf][lb + 2048]), 16, 0, 0);
    __builtin_amdgcn_global_load_lds(AS1(gB0 + k0), AS3(&Bs[buf][lb]), 16, 0, 0);
    __builtin_amdgcn_global_load_lds(AS1(gB1 + k0), AS3(&Bs[buf][lb + 2048]), 16, 0, 0);
  };

  issue(0, 0);
  int cur = 0;
  const int sw = (l16 >> 1) & 3;
  for (int step = 0; step < DIM_C / 32; ++step) {
    __syncthreads();
    if (step + 1 < DIM_C / 32) issue(cur ^ 1, (step + 1) * 32);

    bf16x8 aF[4], bF[4];
#pragma unroll
    for (int mi = 0; mi < 4; ++mi)
      aF[mi] = *reinterpret_cast<const bf16x8*>(
          &As[cur][(wm + mi * 16 + l16) * 32 + ((quad ^ sw) * 8)]);
#pragma unroll
    for (int ni = 0; ni < 4; ++ni)
      bF[ni] = *reinterpret_cast<const bf16x8*>(
          &Bs[cur][(wn + ni * 16 + l16) * 32 + ((quad ^ sw) * 8)]);
#pragma unroll
    for (int mi = 0; mi < 4; ++mi)
#pragma unroll
      for (int ni = 0; ni < 4; ++ni)
        acc[mi][ni] = __builtin_amdgcn_mfma_f32_16x16x32_bf16(aF[mi], bF[ni],
                                                              acc[mi][ni], 0, 0, 0);
    cur ^= 1;
  }

#pragma unroll
  for (int mi = 0; mi < 4; ++mi) {
#pragma unroll
    for (int ni = 0; ni < 4; ++ni) {
      const int gmB = m0 + wm + mi * 16 + quad * 4;
      const int gn = n0 + wn + ni * 16 + l16;
      const float bv = bias[gn];
#pragma unroll
      for (int r = 0; r < 4; ++r)
        out[(size_t)(gmB + r) * DIM_C + gn] = acc[mi][ni][r] + bv;
    }
  }
}

// ---------------------------------------------------------------------------
// Flash attention, barrier-free K-loop, 2-deep K-register pipeline.
// K''/V'' pre-fragmented layouts read directly from global (lane*16B
// coalesced). 512-thread blocks: waves 0-3 = keys [0,half), waves 4-7 =
// [half,cntPad); partials exactly additive (max-free exp2 softmax), merged
// via LDS at the end. V frags issued at chunk start so their latency drains
// under QK-MFMA + exp2.
// ---------------------------------------------------------------------------
__global__ __launch_bounds__(512, 3) void attn_kernel(
    const bf16_t* __restrict__ q, const bf16_t* __restrict__ kfr,
    const bf16_t* __restrict__ vfr, const bf16_t* __restrict__ wp,
    const int* __restrict__ cnts, bf16_t* __restrict__ ctx) {
  __shared__ __align__(16) bf16_t Ps[8][1024];  // per-wave P (swizzled)
  __shared__ float Om[4][16][65];               // group-0 partial O
  __shared__ float Lm[64];                      // group-0 partial l

  const int tid = threadIdx.x;
  const int wave = tid >> 6, lane = tid & 63;
  const int quad = lane >> 4, l16 = lane & 15;
  const int g = wave >> 2, wsub = wave & 3;
  const int bh = blockIdx.y;
  const int b = bh / NUM_H, h = bh - b * NUM_H;
  const int q0 = blockIdx.x * 64 + wsub * 16;
  const int cntPad = cnts[b * 2];  // multiple of 64
  const int half = ((cntPad >> 1) + 63) & ~63;
  const int kbeg = g ? half : 0;
  const int kend = g ? cntPad : half;

  const bf16_t* qb = q + (size_t)bh * SEQ_N * HEAD_D;
  const bf16_t* kbase = kfr + (size_t)bh * 128 * 1024;  // [c][h][512]
  const bf16_t* vbase = vfr + (size_t)bh * 64 * 2048;   // [kc][dt][512]
  const bf16_t* wb = wp + (size_t)b * SEQ_N;

  bf16x8 qf[2];
#pragma unroll
  for (int ks = 0; ks < 2; ++ks)
    qf[ks] = *reinterpret_cast<const bf16x8*>(
        &qb[(size_t)(q0 + l16) * HEAD_D + ks * 32 + quad * 8]);

  f32x4 acc[4] = {};
  f32x4 acc_l = {};

  const int swz = l16 & 7;
  const int psbase = wave * 1024 + l16 * 64;

  auto loadK = [&](int key0, bf16x8 kf[4][2]) {
    const bf16_t* p = kbase + (size_t)(key0 >> 4) * 1024 + lane * 8;
#pragma unroll
    for (int kt = 0; kt < 4; ++kt) {
      kf[kt][0] = *reinterpret_cast<const bf16x8*>(p + kt * 1024);
      kf[kt][1] = *reinterpret_cast<const bf16x8*>(p + kt * 1024 + 512);
    }
  };

  auto chunk = [&](int key0, bf16x8 kf[4][2]) {
    // V frags issued first: latency drains under QK MFMA + exp2
    const bf16_t* vp = vbase + (size_t)(key0 >> 5) * 2048 + lane * 8;
    bf16x8 vf[2][4];
#pragma unroll
    for (int kc = 0; kc < 2; ++kc)
#pragma unroll
      for (int dt = 0; dt < 4; ++dt)
        vf[kc][dt] = *reinterpret_cast<const bf16x8*>(vp + kc * 2048 + dt * 512);

    // ---- S^T = K·Q^T ----
    f32x4 s[4];
#pragma unroll
    for (int kt = 0; kt < 4; ++kt) {
      f32x4 z = {0.0f, 0.0f, 0.0f, 0.0f};
      z = __builtin_amdgcn_mfma_f32_16x16x32_bf16(kf[kt][0], qf[0], z, 0, 0, 0);
      s[kt] = __builtin_amdgcn_mfma_f32_16x16x32_bf16(kf[kt][1], qf[1], z, 0, 0, 0);
    }

    // ---- p = exp2(s); pack into swizzled per-wave Ps ----
#pragma unroll
    for (int kt = 0; kt < 4; ++kt) {
      union { ushort4 u; bf16_t h4[4]; } pk;
      pk.h4[0] = (bf16_t)exp2f(s[kt][0]);
      pk.h4[1] = (bf16_t)exp2f(s[kt][1]);
      pk.h4[2] = (bf16_t)exp2f(s[kt][2]);
      pk.h4[3] = (bf16_t)exp2f(s[kt][3]);
      const int c = kt * 2 + (quad >> 1);
      *reinterpret_cast<ushort4*>(
          &Ps[0][psbase + ((c ^ swz) << 3) + ((quad & 1) << 2)]) = pk.u;
    }

    bf16x8 pf0 = *reinterpret_cast<const bf16x8*>(
        &Ps[0][psbase + ((quad ^ swz) << 3)]);
    bf16x8 pf1 = *reinterpret_cast<const bf16x8*>(
        &Ps[0][psbase + (((4 + quad) ^ swz) << 3)]);
    bf16x8 wf0 = *reinterpret_cast<const bf16x8*>(&wb[key0 + quad * 8]);
    bf16x8 wf1 = *reinterpret_cast<const bf16x8*>(&wb[key0 + 32 + quad * 8]);
    acc_l = __builtin_amdgcn_mfma_f32_16x16x32_bf16(pf0, wf0, acc_l, 0, 0, 0);
    acc_l = __builtin_amdgcn_mfma_f32_16x16x32_bf16(pf1, wf1, acc_l, 0, 0, 0);

#pragma unroll
    for (int dt = 0; dt < 4; ++dt) {
      acc[dt] = __builtin_amdgcn_mfma_f32_16x16x32_bf16(pf0, vf[0][dt], acc[dt], 0, 0, 0);
      acc[dt] = __builtin_amdgcn_mfma_f32_16x16x32_bf16(pf1, vf[1][dt], acc[dt], 0, 0, 0);
    }
  };

  if (kbeg < kend) {
    bf16x8 kfA[4][2], kfB[4][2];
    loadK(kbeg, kfA);
    int key0 = kbeg;
    while (true) {
      if (key0 + 64 < kend) loadK(key0 + 64, kfB);
      chunk(key0, kfA);
      key0 += 64;
      if (key0 >= kend) break;
      if (key0 + 64 < kend) loadK(key0 + 64, kfA);
      chunk(key0, kfB);
      key0 += 64;
      if (key0 >= kend) break;
    }
  }

  // ---- merge the two key-splits (exact: partials are additive) ----
  if (g == 0) {
#pragma unroll
    for (int dt = 0; dt < 4; ++dt)
#pragma unroll
      for (int r = 0; r < 4; ++r)
        Om[wsub][quad * 4 + r][dt * 16 + l16] = acc[dt][r];
    if (l16 == 0) {
#pragma unroll
      for (int r = 0; r < 4; ++r) Lm[wsub * 16 + quad * 4 + r] = acc_l[r];
    }
  }
  __syncthreads();
  if (g == 1) {
    float rl[4];
#pragma unroll
    for (int r = 0; r < 4; ++r)
      rl[r] = 1.0f / (acc_l[r] + Lm[wsub * 16 + quad * 4 + r]);
#pragma unroll
    for (int dt = 0; dt < 4; ++dt)
#pragma unroll
      for (int r = 0; r < 4; ++r) {
        const int tok = q0 + quad * 4 + r;
        const float val =
            (acc[dt][r] + Om[wsub][quad * 4 + r][dt * 16 + l16]) * rl[r];
        ctx[((size_t)b * SEQ_N + tok) * DIM_C + h * HEAD_D + dt * 16 + l16] =
            (bf16_t)val;
      }
  }
}

// ---------------------------------------------------------------------------
extern "C" void kernel_launch(void* const* d_in, const int* in_sizes, int n_in,
                              void* d_out, int out_size, void* d_ws,
                              size_t ws_size, hipStream_t stream) {
  const float* x = (const float*)d_in[0];       // [B,N,C] f32
  const float* mask = (const float*)d_in[1];    // [B,N]   f32
  const float* qkv_w = (const float*)d_in[2];   // [3C,C]  f32
  const float* proj_w = (const float*)d_in[3];  // [C,C]   f32
  const float* proj_b = (const float*)d_in[4];  // [C]     f32
  float* out = (float*)d_out;                   // [B,N,C] f32

  const size_t nx = (size_t)MTOK * DIM_C;
  const size_t nqw = (size_t)3 * DIM_C * DIM_C;
  const size_t npw = (size_t)DIM_C * DIM_C;
  const size_t per = (size_t)BH_CNT * SEQ_N * HEAD_D;

  bf16_t* xb = (bf16_t*)d_ws;
  bf16_t* qwb = xb + nx;
  bf16_t* pwb = qwb + nqw;
  bf16_t* wpb = pwb + npw;            // [B,N] bf16 w' (1 visible / 0 pad)
  int* srcb = (int*)(wpb + MTOK);     // [B*N] compacted->orig token
  int* cntsb = srcb + MTOK;           // [B*2]: cntPad64, count
  bf16_t* qkv = (bf16_t*)(cntsb + 8); // Q [B,H,N,D]; K'' frag; V'' frag
  bf16_t* ctx = qkv + 3 * per;        // [B,N,C]

  const int nb0 = (int)(nx / 2048), nb1 = (int)(nqw / 2048),
            nb2 = (int)(npw / 2048);

  cvt_scan_kernel<<<nb0 + nb1 + nb2 + NUM_B, 256, 0, stream>>>(
      x, qkv_w, proj_w, mask, xb, qwb, pwb, srcb, wpb, cntsb, nb0, nb1, nb2);
  gemm_qkv_kernel<<<dim3(3 * DIM_C / 128, MTOK / 128), 256, 0, stream>>>(
      xb, qwb, srcb, cntsb, qkv);
  attn_kernel<<<dim3(SEQ_N / 64, BH_CNT), 512, 0, stream>>>(
      qkv, qkv + per, qkv + 2 * per, wpb, cntsb, ctx);
  gemm_proj_kernel<<<dim3(DIM_C / 128, MTOK / 128), 256, 0, stream>>>(
      ctx, pwb, proj_b, out);
}

// Round 11
// 148.292 us; speedup vs baseline: 1.1035x; 1.1035x over previous
//
#include <hip/hip_runtime.h>

typedef __bf16 bf16_t;
typedef __bf16 bf16x8 __attribute__((ext_vector_type(8)));
typedef float f32x4 __attribute__((ext_vector_type(4)));

#define NUM_B 2
#define NUM_H 12
#define SEQ_N 2048
#define DIM_C 768
#define HEAD_D 64
#define BH_CNT (NUM_B * NUM_H)
#define MTOK (NUM_B * SEQ_N)
// qk-scale 1/8 folded with log2(e) so softmax is a bare exp2
#define QSCALE 0.1803368801111137f

#define AS1(p) ((const __attribute__((address_space(1))) void*)(p))
#define AS3(p) ((__attribute__((address_space(3))) void*)(p))

// K'' layout: [bh][c=pos/16][ks=d/32] block of 512 = [quad=d%32/8][l16=pos%16][j=d%8]
// V'' layout: [bh][kc=pos/32][dt=d/16] block of 512 = [quad=pos%32/8][l16=d%16][j=pos%8]
// -> both stage to LDS as straight memcpy and read back as lane*16B frags.

// ---------------------------------------------------------------------------
// f32 -> bf16 bulk convert (x, qkv_w, proj_w); final NUM_B blocks do the
// mask scan (stable partition, w', counts).
// ---------------------------------------------------------------------------
__global__ __launch_bounds__(256) void cvt_scan_kernel(
    const float* __restrict__ s0, const float* __restrict__ s1,
    const float* __restrict__ s2, const float* __restrict__ msk,
    bf16_t* __restrict__ d0, bf16_t* __restrict__ d1, bf16_t* __restrict__ d2,
    int* __restrict__ src, bf16_t* __restrict__ wp, int* __restrict__ cnts,
    int nb0, int nb1, int nb2) {
  __shared__ int psum[256];
  const int blk = blockIdx.x;
  const int t = threadIdx.x;
  if (blk >= nb0 + nb1 + nb2) {
    const int b = blk - (nb0 + nb1 + nb2);
    const float* mb = msk + (size_t)b * SEQ_N;
    int vis[8], c = 0;
#pragma unroll
    for (int j = 0; j < 8; ++j) {
      vis[j] = (mb[t * 8 + j] == 0.0f) ? 1 : 0;
      c += vis[j];
    }
    psum[t] = c;
    __syncthreads();
    for (int off = 1; off < 256; off <<= 1) {
      int v = (t >= off) ? psum[t - off] : 0;
      __syncthreads();
      psum[t] += v;
      __syncthreads();
    }
    const int total = psum[255];
    int vpos = psum[t] - c;
    int mpos = total + (t * 8 - (psum[t] - c));
#pragma unroll
    for (int j = 0; j < 8; ++j) {
      const int tok = t * 8 + j;
      if (vis[j]) {
        src[b * SEQ_N + vpos] = b * SEQ_N + tok;
        wp[b * SEQ_N + vpos] = (bf16_t)1.0f;
        ++vpos;
      } else {
        src[b * SEQ_N + mpos] = b * SEQ_N + tok;
        wp[b * SEQ_N + mpos] = (bf16_t)0.0f;
        ++mpos;
      }
    }
    if (t == 0) {
      cnts[b * 2] = (total + 63) & ~63;
      cnts[b * 2 + 1] = total;
    }
    return;
  }
  const float* sp;
  bf16_t* dp;
  size_t off;
  if (blk < nb0) {
    sp = s0; dp = d0; off = (size_t)blk * 2048;
  } else if (blk < nb0 + nb1) {
    sp = s1; dp = d1; off = (size_t)(blk - nb0) * 2048;
  } else {
    sp = s2; dp = d2; off = (size_t)(blk - nb0 - nb1) * 2048;
  }
  const size_t i = off + (size_t)t * 8;
  float4 f0 = *reinterpret_cast<const float4*>(&sp[i]);
  float4 f1 = *reinterpret_cast<const float4*>(&sp[i + 4]);
  union { ushort4 u; bf16_t h[4]; } p0, p1;
  p0.h[0] = (bf16_t)f0.x; p0.h[1] = (bf16_t)f0.y;
  p0.h[2] = (bf16_t)f0.z; p0.h[3] = (bf16_t)f0.w;
  p1.h[0] = (bf16_t)f1.x; p1.h[1] = (bf16_t)f1.y;
  p1.h[2] = (bf16_t)f1.z; p1.h[3] = (bf16_t)f1.w;
  *reinterpret_cast<ushort4*>(&dp[i]) = p0.u;
  *reinterpret_cast<ushort4*>(&dp[i + 4]) = p1.u;
}

// ---------------------------------------------------------------------------
// QKV GEMM (128x128 tile, glls 16B, XOR swizzle, dbuf).
// n0<768: Q (x QSCALE) -> [B,H,N,D].   768..1535: K -> K'' frag layout.
// n0>=1536: V -> V'' frag layout (pad keys zeroed). All-pad blocks exit.
// ---------------------------------------------------------------------------
__global__ __launch_bounds__(256, 3) void gemm_qkv_kernel(
    const bf16_t* __restrict__ A, const bf16_t* __restrict__ W,
    const int* __restrict__ src, const int* __restrict__ cnts,
    bf16_t* __restrict__ out) {
  __shared__ __align__(16) bf16_t As[2][128 * 32];
  __shared__ __align__(16) bf16_t Bs[2][128 * 32];

  const int tid = threadIdx.x;
  const int wave = tid >> 6, lane = tid & 63;
  const int quad = lane >> 4, l16 = lane & 15;
  const int m0 = blockIdx.y * 128, n0 = blockIdx.x * 128;
  const int wm = (wave >> 1) * 64, wn = (wave & 1) * 64;
  const bool isQ = (n0 < DIM_C);

  if (!isQ) {
    const int b = m0 >> 11;
    if ((m0 & 2047) >= cnts[b * 2]) return;
  }

  f32x4 acc[4][4] = {};

  const int srow = tid >> 2;
  const int scol = ((tid & 3) ^ ((tid >> 3) & 3)) * 8;
  int ar0, ar1;
  if (isQ) {
    ar0 = m0 + srow;
    ar1 = m0 + srow + 64;
  } else {
    ar0 = src[m0 + srow];
    ar1 = src[m0 + srow + 64];
  }
  const bf16_t* gA0 = A + (size_t)ar0 * DIM_C + scol;
  const bf16_t* gA1 = A + (size_t)ar1 * DIM_C + scol;
  const bf16_t* gB0 = W + (size_t)(n0 + srow) * DIM_C + scol;
  const bf16_t* gB1 = W + (size_t)(n0 + srow + 64) * DIM_C + scol;
  const int lb = wave * 512;

  auto issue = [&](int buf, int k0) {
    __builtin_amdgcn_global_load_lds(AS1(gA0 + k0), AS3(&As[buf][lb]), 16, 0, 0);
    __builtin_amdgcn_global_load_lds(AS1(gA1 + k0), AS3(&As[buf][lb + 2048]), 16, 0, 0);
    __builtin_amdgcn_global_load_lds(AS1(gB0 + k0), AS3(&Bs[buf][lb]), 16, 0, 0);
    __builtin_amdgcn_global_load_lds(AS1(gB1 + k0), AS3(&Bs[buf][lb + 2048]), 16, 0, 0);
  };

  issue(0, 0);
  int cur = 0;
  const int sw = (l16 >> 1) & 3;
  for (int step = 0; step < DIM_C / 32; ++step) {
    __syncthreads();
    if (step + 1 < DIM_C / 32) issue(cur ^ 1, (step + 1) * 32);

    bf16x8 aF[4], bF[4];
#pragma unroll
    for (int mi = 0; mi < 4; ++mi)
      aF[mi] = *reinterpret_cast<const bf16x8*>(
          &As[cur][(wm + mi * 16 + l16) * 32 + ((quad ^ sw) * 8)]);
#pragma unroll
    for (int ni = 0; ni < 4; ++ni)
      bF[ni] = *reinterpret_cast<const bf16x8*>(
          &Bs[cur][(wn + ni * 16 + l16) * 32 + ((quad ^ sw) * 8)]);
#pragma unroll
    for (int mi = 0; mi < 4; ++mi)
#pragma unroll
      for (int ni = 0; ni < 4; ++ni)
        acc[mi][ni] = __builtin_amdgcn_mfma_f32_16x16x32_bf16(aF[mi], bF[ni],
                                                              acc[mi][ni], 0, 0, 0);
    cur ^= 1;
  }

  const size_t per = (size_t)BH_CNT * SEQ_N * HEAD_D;
#pragma unroll
  for (int mi = 0; mi < 4; ++mi) {
#pragma unroll
    for (int ni = 0; ni < 4; ++ni) {
      const int gmB = m0 + wm + mi * 16 + quad * 4;
      const int gn = n0 + wn + ni * 16 + l16;
      const int b = gmB >> 11;
      if (isQ) {
        const int h = gn >> 6, d = gn & 63;
#pragma unroll
        for (int r = 0; r < 4; ++r) {
          const int gm = gmB + r;
          const int tok = gm & 2047;
          out[(((size_t)((gm >> 11) * NUM_H + h) * SEQ_N + tok) * HEAD_D + d)] =
              (bf16_t)(acc[mi][ni][r] * QSCALE);
        }
      } else if (n0 < 2 * DIM_C) {  // K -> K'' fragment layout
        const int rem = gn - DIM_C;
        const int hh = rem >> 6, d = rem & 63;
        const int posm = gmB & 2047;
        const int bh = b * NUM_H + hh;
        const size_t base = per +
            (((size_t)(bh * 128 + (posm >> 4)) * 2 + (d >> 5)) * 512 +
             ((d >> 3) & 3) * 128 + (d & 7));
        const int l16k = posm & 15;
#pragma unroll
        for (int r = 0; r < 4; ++r)
          out[base + (size_t)(l16k + r) * 8] = (bf16_t)acc[mi][ni][r];
      } else {  // V -> V'' fragment layout, zero pad keys
        const int rem = gn - 2 * DIM_C;
        const int hh = rem >> 6, d = rem & 63;
        const int posm = gmB & 2047;
        const int bh = b * NUM_H + hh;
        const int count = cnts[b * 2 + 1];
        const size_t base = 2 * per +
            (((size_t)(bh * 64 + (posm >> 5)) * 4 + (d >> 4)) * 512 +
             ((posm >> 3) & 3) * 128 + (d & 15) * 8 + (posm & 7));
        union { ushort4 u; bf16_t h4[4]; } pk;
#pragma unroll
        for (int r = 0; r < 4; ++r)
          pk.h4[r] = (posm + r < count) ? (bf16_t)acc[mi][ni][r] : (bf16_t)0.0f;
        *reinterpret_cast<ushort4*>(&out[base]) = pk.u;
      }
    }
  }
}

// ---------------------------------------------------------------------------
// Proj GEMM: out = ctx @ proj_w^T + bias, f32 out. 128x128, glls, dbuf.
// ---------------------------------------------------------------------------
__global__ __launch_bounds__(256, 3) void gemm_proj_kernel(
    const bf16_t* __restrict__ A, const bf16_t* __restrict__ W,
    const float* __restrict__ bias, float* __restrict__ out) {
  __shared__ __align__(16) bf16_t As[2][128 * 32];
  __shared__ __align__(16) bf16_t Bs[2][128 * 32];

  const int tid = threadIdx.x;
  const int wave = tid >> 6, lane = tid & 63;
  const int quad = lane >> 4, l16 = lane & 15;
  const int m0 = blockIdx.y * 128, n0 = blockIdx.x * 128;
  const int wm = (wave >> 1) * 64, wn = (wave & 1) * 64;

  f32x4 acc[4][4] = {};

  const int srow = tid >> 2;
  const int scol = ((tid & 3) ^ ((tid >> 3) & 3)) * 8;
  const bf16_t* gA0 = A + (size_t)(m0 + srow) * DIM_C + scol;
  const bf16_t* gA1 = A + (size_t)(m0 + srow + 64) * DIM_C + scol;
  const bf16_t* gB0 = W + (size_t)(n0 + srow) * DIM_C + scol;
  const bf16_t* gB1 = W + (size_t)(n0 + srow + 64) * DIM_C + scol;
  const int lb = wave * 512;

  auto issue = [&](int buf, int k0) {
    __builtin_amdgcn_global_load_lds(AS1(gA0 + k0), AS3(&As[buf][lb]), 16, 0, 0);
    __builtin_amdgcn_global_load_lds(AS1(gA1 + k0), AS3(&As[buf][lb + 2048]), 16, 0, 0);
    __builtin_amdgcn_global_load_lds(AS1(gB0 + k0), AS3(&Bs[buf][lb]), 16, 0, 0);
    __builtin_amdgcn_global_load_lds(AS1(gB1 + k0), AS3(&Bs[buf][lb + 2048]), 16, 0, 0);
  };

  issue(0, 0);
  int cur = 0;
  const int sw = (l16 >> 1) & 3;
  for (int step = 0; step < DIM_C / 32; ++step) {
    __syncthreads();
    if (step + 1 < DIM_C / 32) issue(cur ^ 1, (step + 1) * 32);

    bf16x8 aF[4], bF[4];
#pragma unroll
    for (int mi = 0; mi < 4; ++mi)
      aF[mi] = *reinterpret_cast<const bf16x8*>(
          &As[cur][(wm + mi * 16 + l16) * 32 + ((quad ^ sw) * 8)]);
#pragma unroll
    for (int ni = 0; ni < 4; ++ni)
      bF[ni] = *reinterpret_cast<const bf16x8*>(
          &Bs[cur][(wn + ni * 16 + l16) * 32 + ((quad ^ sw) * 8)]);
#pragma unroll
    for (int mi = 0; mi < 4; ++mi)
#pragma unroll
      for (int ni = 0; ni < 4; ++ni)
        acc[mi][ni] = __builtin_amdgcn_mfma_f32_16x16x32_bf16(aF[mi], bF[ni],
                                                              acc[mi][ni], 0, 0, 0);
    cur ^= 1;
  }

#pragma unroll
  for (int mi = 0; mi < 4; ++mi) {
#pragma unroll
    for (int ni = 0; ni < 4; ++ni) {
      const int gmB = m0 + wm + mi * 16 + quad * 4;
      const int gn = n0 + wn + ni * 16 + l16;
      const float bv = bias[gn];
#pragma unroll
      for (int r = 0; r < 4; ++r)
        out[(size_t)(gmB + r) * DIM_C + gn] = acc[mi][ni][r] + bv;
    }
  }
}

// ---------------------------------------------------------------------------
// Flash attention: 512-thread blocks over 64 queries; 2 groups x 4 waves
// split the key range; each group LDS-stages ITS half (shared by its 4 waves
// -> low L2 traffic), dbuf, one block barrier per chunk (groups in
// lockstep). K''/V'' fragment layouts make staging a straight memcpy and
// LDS frag reads linear/conflict-free. Max-free exp2 softmax; partial O,l
// merged exactly at the end through re-used LDS.
// ---------------------------------------------------------------------------
__global__ __launch_bounds__(512, 4) void attn_kernel(
    const bf16_t* __restrict__ q, const bf16_t* __restrict__ kfr,
    const bf16_t* __restrict__ vfr, const bf16_t* __restrict__ wp,
    const int* __restrict__ cnts, bf16_t* __restrict__ ctx) {
  __shared__ __align__(16) char smem[81920];  // 80KB -> 2 blocks/CU
  bf16_t* Ks = (bf16_t*)smem;                 // [g*2+buf][4096]
  bf16_t* Vs = (bf16_t*)(smem + 32768);       // [g*2+buf][4096]
  bf16_t* Ps = (bf16_t*)(smem + 65536);       // [wave][1024]
  float* Om = (float*)smem;                   // merge: [wsub][16][65] (aliases Ks)
  float* Lm = (float*)(smem + 16640);         // merge: [64]

  const int tid = threadIdx.x;
  const int wave = tid >> 6, lane = tid & 63;
  const int quad = lane >> 4, l16 = lane & 15;
  const int g = wave >> 2, wsub = wave & 3;
  const int bh = blockIdx.y;
  const int b = bh / NUM_H, h = bh - b * NUM_H;
  const int q0 = blockIdx.x * 64 + wsub * 16;
  const int cntPad = cnts[b * 2];               // multiple of 64
  const int half = ((cntPad >> 1) + 63) & ~63;  // g0:[0,half) g1:[half,cntPad)
  const int kbeg = g ? half : 0;
  const int kend = g ? cntPad : half;
  const int nIter = half >> 6;  // g0 chunk count >= g1 chunk count

  const bf16_t* qb = q + (size_t)bh * SEQ_N * HEAD_D;
  const bf16_t* kbase = kfr + (size_t)bh * 128 * 1024;
  const bf16_t* vbase = vfr + (size_t)bh * 64 * 2048;
  const bf16_t* wb = wp + (size_t)b * SEQ_N;

  bf16x8 qf[2];
#pragma unroll
  for (int ks = 0; ks < 2; ++ks)
    qf[ks] = *reinterpret_cast<const bf16x8*>(
        &qb[(size_t)(q0 + l16) * HEAD_D + ks * 32 + quad * 8]);

  f32x4 acc[4] = {};
  f32x4 acc_l = {};

  // group-local staging: chunk (8KB K + 8KB V) split across the group's
  // 4 waves, 2 glls each per tensor; straight memcpy in fragment order.
  auto stage = [&](int buf, int key0) {
    const bf16_t* kp = kbase + (size_t)(key0 >> 4) * 1024 + wsub * 1024 + lane * 8;
    const bf16_t* vp = vbase + (size_t)(key0 >> 5) * 2048 + wsub * 1024 + lane * 8;
    bf16_t* kd = Ks + (g * 2 + buf) * 4096 + wsub * 1024;
    bf16_t* vd = Vs + (g * 2 + buf) * 4096 + wsub * 1024;
    __builtin_amdgcn_global_load_lds(AS1(kp), AS3(kd), 16, 0, 0);
    __builtin_amdgcn_global_load_lds(AS1(kp + 512), AS3(kd + 512), 16, 0, 0);
    __builtin_amdgcn_global_load_lds(AS1(vp), AS3(vd), 16, 0, 0);
    __builtin_amdgcn_global_load_lds(AS1(vp + 512), AS3(vd + 512), 16, 0, 0);
  };

  const int swz = l16 & 7;
  const int psbase = wave * 1024 + l16 * 64;

  if (kbeg < kend) stage(0, kbeg);
  int buf = 0;
  for (int i = 0; i < nIter; ++i) {
    __syncthreads();
    const int key0 = kbeg + i * 64;
    const int nxt = key0 + 64;
    if (nxt < kend) stage(buf ^ 1, nxt);

    if (key0 < kend) {
      const int base = (g * 2 + buf) * 4096;
      // ---- S^T = K.Q^T (frag reads linear, conflict-free) ----
      f32x4 s[4];
#pragma unroll
      for (int kt = 0; kt < 4; ++kt) {
        bf16x8 kf0 = *reinterpret_cast<const bf16x8*>(
            &Ks[base + kt * 1024 + lane * 8]);
        bf16x8 kf1 = *reinterpret_cast<const bf16x8*>(
            &Ks[base + kt * 1024 + 512 + lane * 8]);
        f32x4 z = {0.0f, 0.0f, 0.0f, 0.0f};
        z = __builtin_amdgcn_mfma_f32_16x16x32_bf16(kf0, qf[0], z, 0, 0, 0);
        s[kt] = __builtin_amdgcn_mfma_f32_16x16x32_bf16(kf1, qf[1], z, 0, 0, 0);
      }

      // ---- p = exp2(s); pack into swizzled per-wave Ps ----
#pragma unroll
      for (int kt = 0; kt < 4; ++kt) {
        union { ushort4 u; bf16_t h4[4]; } pk;
        pk.h4[0] = (bf16_t)exp2f(s[kt][0]);
        pk.h4[1] = (bf16_t)exp2f(s[kt][1]);
        pk.h4[2] = (bf16_t)exp2f(s[kt][2]);
        pk.h4[3] = (bf16_t)exp2f(s[kt][3]);
        const int c = kt * 2 + (quad >> 1);
        *reinterpret_cast<ushort4*>(
            &Ps[psbase + ((c ^ swz) << 3) + ((quad & 1) << 2)]) = pk.u;
      }

      bf16x8 pf0 = *reinterpret_cast<const bf16x8*>(
          &Ps[psbase + ((quad ^ swz) << 3)]);
      bf16x8 pf1 = *reinterpret_cast<const bf16x8*>(
          &Ps[psbase + (((4 + quad) ^ swz) << 3)]);
      bf16x8 wf0 = *reinterpret_cast<const bf16x8*>(&wb[key0 + quad * 8]);
      bf16x8 wf1 = *reinterpret_cast<const bf16x8*>(&wb[key0 + 32 + quad * 8]);
      acc_l = __builtin_amdgcn_mfma_f32_16x16x32_bf16(pf0, wf0, acc_l, 0, 0, 0);
      acc_l = __builtin_amdgcn_mfma_f32_16x16x32_bf16(pf1, wf1, acc_l, 0, 0, 0);

      // ---- PV ----
#pragma unroll
      for (int dt = 0; dt < 4; ++dt) {
        bf16x8 vf0 = *reinterpret_cast<const bf16x8*>(
            &Vs[base + dt * 512 + lane * 8]);
        bf16x8 vf1 = *reinterpret_cast<const bf16x8*>(
            &Vs[base + 2048 + dt * 512 + lane * 8]);
        acc[dt] = __builtin_amdgcn_mfma_f32_16x16x32_bf16(pf0, vf0, acc[dt], 0, 0, 0);
        acc[dt] = __builtin_amdgcn_mfma_f32_16x16x32_bf16(pf1, vf1, acc[dt], 0, 0, 0);
      }
    }
    buf ^= 1;
  }

  // ---- merge the two key-splits (exact: partials are additive) ----
  __syncthreads();  // done reading Ks before aliasing it as Om
  if (g == 0) {
#pragma unroll
    for (int dt = 0; dt < 4; ++dt)
#pragma unroll
      for (int r = 0; r < 4; ++r)
        Om[(wsub * 16 + quad * 4 + r) * 65 + dt * 16 + l16] = acc[dt][r];
    if (l16 == 0) {
#pragma unroll
      for (int r = 0; r < 4; ++r) Lm[wsub * 16 + quad * 4 + r] = acc_l[r];
    }
  }
  __syncthreads();
  if (g == 1) {
    float rl[4];
#pragma unroll
    for (int r = 0; r < 4; ++r)
      rl[r] = 1.0f / (acc_l[r] + Lm[wsub * 16 + quad * 4 + r]);
#pragma unroll
    for (int dt = 0; dt < 4; ++dt)
#pragma unroll
      for (int r = 0; r < 4; ++r) {
        const int tok = q0 + quad * 4 + r;
        const float val =
            (acc[dt][r] + Om[(wsub * 16 + quad * 4 + r) * 65 + dt * 16 + l16]) *
            rl[r];
        ctx[((size_t)b * SEQ_N + tok) * DIM_C + h * HEAD_D + dt * 16 + l16] =
            (bf16_t)val;
      }
  }
}

// ---------------------------------------------------------------------------
extern "C" void kernel_launch(void* const* d_in, const int* in_sizes, int n_in,
                              void* d_out, int out_size, void* d_ws,
                              size_t ws_size, hipStream_t stream) {
  const float* x = (const float*)d_in[0];       // [B,N,C] f32
  const float* mask = (const float*)d_in[1];    // [B,N]   f32
  const float* qkv_w = (const float*)d_in[2];   // [3C,C]  f32
  const float* proj_w = (const float*)d_in[3];  // [C,C]   f32
  const float* proj_b = (const float*)d_in[4];  // [C]     f32
  float* out = (float*)d_out;                   // [B,N,C] f32

  const size_t nx = (size_t)MTOK * DIM_C;
  const size_t nqw = (size_t)3 * DIM_C * DIM_C;
  const size_t npw = (size_t)DIM_C * DIM_C;
  const size_t per = (size_t)BH_CNT * SEQ_N * HEAD_D;

  bf16_t* xb = (bf16_t*)d_ws;
  bf16_t* qwb = xb + nx;
  bf16_t* pwb = qwb + nqw;
  bf16_t* wpb = pwb + npw;            // [B,N] bf16 w' (1 visible / 0 pad)
  int* srcb = (int*)(wpb + MTOK);     // [B*N] compacted->orig token
  int* cntsb = srcb + MTOK;           // [B*2]: cntPad64, count
  bf16_t* qkv = (bf16_t*)(cntsb + 8); // Q [B,H,N,D]; K'' frag; V'' frag
  bf16_t* ctx = qkv + 3 * per;        // [B,N,C]

  const int nb0 = (int)(nx / 2048), nb1 = (int)(nqw / 2048),
            nb2 = (int)(npw / 2048);

  cvt_scan_kernel<<<nb0 + nb1 + nb2 + NUM_B, 256, 0, stream>>>(
      x, qkv_w, proj_w, mask, xb, qwb, pwb, srcb, wpb, cntsb, nb0, nb1, nb2);
  gemm_qkv_kernel<<<dim3(3 * DIM_C / 128, MTOK / 128), 256, 0, stream>>>(
      xb, qwb, srcb, cntsb, qkv);
  attn_kernel<<<dim3(SEQ_N / 64, BH_CNT), 512, 0, stream>>>(
      qkv, qkv + per, qkv + 2 * per, wpb, cntsb, ctx);
  gemm_proj_kernel<<<dim3(DIM_C / 128, MTOK / 128), 256, 0, stream>>>(
      ctx, pwb, proj_b, out);
}